// Round 1
// baseline (134.878 us; speedup 1.0000x reference)
//
#include <hip/hip_runtime.h>
#include <math.h>

// Problem constants
#define B_ 4
#define CIN_ 32
#define COUT_ 64
#define H_ 32
#define W_ 32
#define K_ 3

// ws layout:
//   feat: float4[B*CIN*H*W]  (cos p, sin p, cos 3p, sin 3p)   = 2 MB
//   coef: float [COUT][CIN][9][8]  (A1..A4 = x-part, B1..B4 = y-part) = 576 KB
#define FEAT_ELEMS (B_ * CIN_ * H_ * W_)      // 131072
#define COEF_OFF_BYTES (FEAT_ELEMS * 16)      // feat is float4
#define NCOEF (CIN_ * COUT_ * 9)              // 18432

__global__ __launch_bounds__(256) void ring_prep(
    const float* __restrict__ x, const float* __restrict__ probe,
    const float* __restrict__ outw, float* __restrict__ feat,
    float* __restrict__ coef) {
  int i = blockIdx.x * 256 + threadIdx.x;
  if (i < FEAT_ELEMS) {
    float p = x[i];
    float s1, c1, s3, c3;
    sincosf(p, &s1, &c1);
    sincosf(3.0f * p, &s3, &c3);
    float4 v;
    v.x = c1; v.y = s1; v.z = c3; v.w = s3;
    ((float4*)feat)[i] = v;
  }
  if (i < NCOEF) {
    // input flat idx: ((c*COUT + o)*3 + k)*3 + l
    int kl = i % 9;
    int co = i / 9;
    int o = co % COUT_;
    int c = co / COUT_;
    float th = probe[i];
    float wv = outw[i];
    float sth, cth, s3th, c3th, sw, cw;
    sincosf(th, &sth, &cth);
    sincosf(3.0f * th, &s3th, &c3th);
    sincosf(wv, &sw, &cw);
    float* dst = coef + ((size_t)(o * CIN_ + c) * 9 + kl) * 8;
    dst[0] = 0.75f * cw * cth;
    dst[1] = 0.75f * cw * sth;
    dst[2] = 0.25f * cw * c3th;
    dst[3] = 0.25f * cw * s3th;
    dst[4] = 0.75f * sw * cth;
    dst[5] = 0.75f * sw * sth;
    dst[6] = 0.25f * sw * c3th;
    dst[7] = 0.25f * sw * s3th;
  }
}

// LDS: 3 rows (h-1..h+1) x 32 c x 34 wcols (w-pad) x 4 feats = 52224 B
#define LDSW 34
#define LDS_FLOATS (3 * CIN_ * LDSW * 4)

__global__ __launch_bounds__(256) void ring_main(
    const float* __restrict__ feat, const float* __restrict__ coef,
    float* __restrict__ out) {
  __shared__ float lds[LDS_FLOATS];

  int blk = blockIdx.x;           // ((b*32 + h)*4 + og)
  int og = blk & 3;
  int h = (blk >> 2) & 31;
  int b = blk >> 7;
  int tid = threadIdx.x;

  // ---- stage 3 padded feature rows into LDS ----
  // entry e = (r*32 + c)*34 + wcol ; value = feat[b,c,h-1+r,wcol-1] or pad(1,0,1,0)
  for (int e = tid; e < 3 * CIN_ * LDSW; e += 256) {
    int r = e / (CIN_ * LDSW);
    int rem = e - r * (CIN_ * LDSW);
    int c = rem / LDSW;
    int wcol = rem - c * LDSW;
    int hs = h - 1 + r;
    int ws = wcol - 1;
    float4 v;
    if (hs >= 0 && hs < H_ && ws >= 0 && ws < W_) {
      v = ((const float4*)feat)[((b * CIN_ + c) * H_ + hs) * W_ + ws];
    } else {
      v.x = 1.0f; v.y = 0.0f; v.z = 1.0f; v.w = 0.0f;  // p = 0 pad
    }
    *(float4*)&lds[e * 4] = v;
  }
  __syncthreads();

  int w = tid & 31;
  int ol = tid >> 5;              // 0..7
  int o0 = og * 16 + ol;
  int o1 = o0 + 8;

  float ax0 = 0.f, ay0 = 0.f, ax1 = 0.f, ay1 = 0.f;

  for (int c = 0; c < CIN_; ++c) {
    const float* cf0 = coef + ((size_t)(o0 * CIN_ + c) * 9) * 8;
    const float* cf1 = coef + ((size_t)(o1 * CIN_ + c) * 9) * 8;
#pragma unroll
    for (int k = 0; k < 3; ++k) {
#pragma unroll
      for (int l = 0; l < 3; ++l) {
        int kl = k * 3 + l;
        float4 f = *(const float4*)&lds[(((k * CIN_ + c) * LDSW) + w + l) * 4];
        float4 a0 = *(const float4*)(cf0 + kl * 8);
        float4 b0 = *(const float4*)(cf0 + kl * 8 + 4);
        float4 a1 = *(const float4*)(cf1 + kl * 8);
        float4 b1 = *(const float4*)(cf1 + kl * 8 + 4);
        ax0 = fmaf(a0.x, f.x, ax0); ax0 = fmaf(a0.y, f.y, ax0);
        ax0 = fmaf(a0.z, f.z, ax0); ax0 = fmaf(a0.w, f.w, ax0);
        ay0 = fmaf(b0.x, f.x, ay0); ay0 = fmaf(b0.y, f.y, ay0);
        ay0 = fmaf(b0.z, f.z, ay0); ay0 = fmaf(b0.w, f.w, ay0);
        ax1 = fmaf(a1.x, f.x, ax1); ax1 = fmaf(a1.y, f.y, ax1);
        ax1 = fmaf(a1.z, f.z, ax1); ax1 = fmaf(a1.w, f.w, ax1);
        ay1 = fmaf(b1.x, f.x, ay1); ay1 = fmaf(b1.y, f.y, ay1);
        ay1 = fmaf(b1.z, f.z, ay1); ay1 = fmaf(b1.w, f.w, ay1);
      }
    }
  }

  out[((b * COUT_ + o0) * H_ + h) * W_ + w] = atan2f(ay0, ax0);
  out[((b * COUT_ + o1) * H_ + h) * W_ + w] = atan2f(ay1, ax1);
}

extern "C" void kernel_launch(void* const* d_in, const int* in_sizes, int n_in,
                              void* d_out, int out_size, void* d_ws, size_t ws_size,
                              hipStream_t stream) {
  const float* x = (const float*)d_in[0];
  const float* probe = (const float*)d_in[1];
  const float* outw = (const float*)d_in[2];
  float* feat = (float*)d_ws;
  float* coef = (float*)((char*)d_ws + COEF_OFF_BYTES);
  float* out = (float*)d_out;

  ring_prep<<<FEAT_ELEMS / 256, 256, 0, stream>>>(x, probe, outw, feat, coef);
  ring_main<<<B_ * H_ * 4, 256, 0, stream>>>(feat, coef, out);
}

// Round 2
// 102.160 us; speedup vs baseline: 1.3203x; 1.3203x over previous
//
#include <hip/hip_runtime.h>
#include <math.h>

// Problem constants
#define B_ 4
#define CIN_ 32
#define COUT_ 64
#define H_ 32
#define W_ 32
#define K_ 3

// ws layout:
//   feat: float4[B*CIN*H*W]  (cos p, sin p, cos 3p, sin 3p)        = 2 MB
//   coef: float [CIN][9][COUT][8] (A1..A4 = x-part, B1..B4 = y-part) = 576 KB
#define FEAT_ELEMS (B_ * CIN_ * H_ * W_)      // 131072
#define COEF_OFF_BYTES (FEAT_ELEMS * 16)      // feat is float4
#define NCOEF (CIN_ * COUT_ * 9)              // 18432

__global__ __launch_bounds__(256) void ring_prep(
    const float* __restrict__ x, const float* __restrict__ probe,
    const float* __restrict__ outw, float* __restrict__ feat,
    float* __restrict__ coef) {
  int i = blockIdx.x * 256 + threadIdx.x;
  if (i < FEAT_ELEMS) {
    float p = x[i];
    float s1, c1;
    __sincosf(p, &s1, &c1);
    // triple-angle (exact identities, cheap)
    float c3 = c1 * fmaf(4.0f * c1, c1, -3.0f);
    float s3 = s1 * fmaf(-4.0f * s1, s1, 3.0f);
    float4 v;
    v.x = c1; v.y = s1; v.z = c3; v.w = s3;
    ((float4*)feat)[i] = v;
  }
  if (i < NCOEF) {
    // input flat idx: ((c*COUT + o)*3 + k)*3 + l
    int kl = i % 9;
    int co = i / 9;
    int o = co % COUT_;
    int c = co / COUT_;
    float th = probe[i];
    float wv = outw[i];
    float sth, cth, sw, cw;
    __sincosf(th, &sth, &cth);
    __sincosf(wv, &sw, &cw);
    float c3th = cth * fmaf(4.0f * cth, cth, -3.0f);
    float s3th = sth * fmaf(-4.0f * sth, sth, 3.0f);
    // blocked layout for LDS staging: [c][kl][o][8]
    float* dst = coef + (((size_t)c * 9 + kl) * COUT_ + o) * 8;
    dst[0] = 0.75f * cw * cth;
    dst[1] = 0.75f * cw * sth;
    dst[2] = 0.25f * cw * c3th;
    dst[3] = 0.25f * cw * s3th;
    dst[4] = 0.75f * sw * cth;
    dst[5] = 0.75f * sw * sth;
    dst[6] = 0.25f * sw * c3th;
    dst[7] = 0.25f * sw * s3th;
  }
}

// LDS: 3 feature rows (h-1..h+1) x 32 c x 34 wcols x float4 = 52224 B
//    + coef chunk: 4 c x 9 kl x 16 o x 8 floats              = 18432 B
// total 70656 B -> 2 blocks/CU
#define LDSW 34
#define CCH 4  // c-chunk size

__global__ __launch_bounds__(256) void ring_main(
    const float4* __restrict__ feat, const float* __restrict__ coef,
    float* __restrict__ out) {
  __shared__ float4 sfeat[3 * CIN_ * LDSW];       // [r][c][wcol]
  __shared__ float4 scoef[CCH * 9 * 16 * 2];      // [cc][kl][o_local][2]

  int blk = blockIdx.x;           // ((b*32 + h)*4 + og)
  int og = blk & 3;               // 16-output group
  int h = (blk >> 2) & 31;
  int b = blk >> 7;
  int tid = threadIdx.x;
  int w = tid & 31;
  int ol = tid >> 5;              // 0..7 -> outputs og*16 + 2*ol, +1

  // ---- stage 3 padded feature rows into LDS ----
  for (int e = tid; e < 3 * CIN_ * LDSW; e += 256) {
    int r = e / (CIN_ * LDSW);
    int rem = e - r * (CIN_ * LDSW);
    int c = rem / LDSW;
    int wc = rem - c * LDSW;
    int hs = h - 1 + r;
    int ws = wc - 1;
    float4 v = make_float4(1.0f, 0.0f, 1.0f, 0.0f);  // p = 0 pad
    if (hs >= 0 && hs < H_ && (unsigned)ws < (unsigned)W_)
      v = feat[((b * CIN_ + c) * H_ + hs) * W_ + ws];
    sfeat[e] = v;
  }

  float ax0 = 0.f, ay0 = 0.f, ax1 = 0.f, ay1 = 0.f;
  int o_base = og * 16;

  for (int ch = 0; ch < CIN_ / CCH; ++ch) {
    __syncthreads();  // first iter: features visible; later: scoef free to overwrite
    // ---- stage coef chunk: CCH*9*32 float4 (contiguous per (c,kl)) ----
    for (int t = tid; t < CCH * 9 * 32; t += 256) {
      int cc = t / (9 * 32);
      int r2 = t - cc * (9 * 32);
      int kl = r2 >> 5;
      int j = r2 & 31;
      const float4* g = (const float4*)(coef +
          (((size_t)(ch * CCH + cc) * 9 + kl) * COUT_ + o_base) * 8);
      scoef[t] = g[j];
    }
    __syncthreads();

#pragma unroll
    for (int cc = 0; cc < CCH; ++cc) {
      int c = ch * CCH + cc;
#pragma unroll
      for (int k = 0; k < 3; ++k) {
#pragma unroll
        for (int l = 0; l < 3; ++l) {
          int kl = k * 3 + l;
          float4 f = sfeat[(k * CIN_ + c) * LDSW + w + l];
          const float4* cf = &scoef[((cc * 9 + kl) * 16 + 2 * ol) * 2];
          float4 a0 = cf[0], b0 = cf[1], a1 = cf[2], b1 = cf[3];
          ax0 = fmaf(a0.x, f.x, ax0); ax0 = fmaf(a0.y, f.y, ax0);
          ax0 = fmaf(a0.z, f.z, ax0); ax0 = fmaf(a0.w, f.w, ax0);
          ay0 = fmaf(b0.x, f.x, ay0); ay0 = fmaf(b0.y, f.y, ay0);
          ay0 = fmaf(b0.z, f.z, ay0); ay0 = fmaf(b0.w, f.w, ay0);
          ax1 = fmaf(a1.x, f.x, ax1); ax1 = fmaf(a1.y, f.y, ax1);
          ax1 = fmaf(a1.z, f.z, ax1); ax1 = fmaf(a1.w, f.w, ax1);
          ay1 = fmaf(b1.x, f.x, ay1); ay1 = fmaf(b1.y, f.y, ay1);
          ay1 = fmaf(b1.z, f.z, ay1); ay1 = fmaf(b1.w, f.w, ay1);
        }
      }
    }
  }

  int o0 = o_base + 2 * ol;
  out[((b * COUT_ + o0) * H_ + h) * W_ + w] = atan2f(ay0, ax0);
  out[((b * COUT_ + o0 + 1) * H_ + h) * W_ + w] = atan2f(ay1, ax1);
}

extern "C" void kernel_launch(void* const* d_in, const int* in_sizes, int n_in,
                              void* d_out, int out_size, void* d_ws, size_t ws_size,
                              hipStream_t stream) {
  const float* x = (const float*)d_in[0];
  const float* probe = (const float*)d_in[1];
  const float* outw = (const float*)d_in[2];
  float* feat = (float*)d_ws;
  float* coef = (float*)((char*)d_ws + COEF_OFF_BYTES);
  float* out = (float*)d_out;

  ring_prep<<<FEAT_ELEMS / 256, 256, 0, stream>>>(x, probe, outw, feat, coef);
  ring_main<<<B_ * H_ * 4, 256, 0, stream>>>((const float4*)feat, coef, out);
}